// Round 1
// baseline (600.597 us; speedup 1.0000x reference)
//
#include <hip/hip_runtime.h>

// Problem constants (from reference): N=262144 coarse voxels, C=64 channels,
// SCALE=2 -> 8 children per voxel.
// Outputs concatenated flat in d_out (read back as float32 by the harness):
//   fine_data: [N*8, 64] fp32   (N*8*64 = 134217728 elems)
//   fine_ijk : [N*8, 3]  int -> stored as float (6291456 elems)
#define N_COARSE 262144
#define CHANNELS 64

// One thread per coarse float4 (16 float4 per coarse row of 64 ch).
// Load once, replicate to the 8 child rows. Coarse data fetched exactly once.
__global__ void __launch_bounds__(256)
upsample_data_kernel(const float4* __restrict__ in, float4* __restrict__ out) {
    const size_t idx = (size_t)blockIdx.x * blockDim.x + threadIdx.x;  // [0, N*16)
    const size_t n  = idx >> 4;   // coarse row
    const size_t c4 = idx & 15;   // float4 index within row
    const float4 v = in[idx];
    float4* base = out + (n * 8) * 16 + c4;
#pragma unroll
    for (int o = 0; o < 8; ++o) {
        base[(size_t)o * 16] = v;
    }
}

// One thread per output ijk element (fully coalesced stores).
// fine row r = e/3, dim d = e%3, parent n = r>>3, child o = r&7.
// offsets (meshgrid ij-order): off[o] = (o>>2, (o>>1)&1, o&1) -> bit (2-d) of o.
__global__ void __launch_bounds__(256)
upsample_ijk_kernel(const int* __restrict__ ijk, float* __restrict__ out) {
    const int e = blockIdx.x * blockDim.x + threadIdx.x;  // [0, N*8*3)
    const int r = e / 3;          // magic-mul, cheap
    const int d = e - r * 3;
    const int n = r >> 3;
    const int o = r & 7;
    const int off = (o >> (2 - d)) & 1;
    out[e] = (float)(ijk[n * 3 + d] * 2 + off);
}

extern "C" void kernel_launch(void* const* d_in, const int* in_sizes, int n_in,
                              void* d_out, int out_size, void* d_ws, size_t ws_size,
                              hipStream_t stream) {
    const float4* coarse_data = (const float4*)d_in[0];
    const int*    coarse_ijk  = (const int*)d_in[1];

    float*  out       = (float*)d_out;
    float4* out_data  = (float4*)out;
    float*  out_ijk   = out + (size_t)N_COARSE * 8 * CHANNELS;  // 134217728

    // Data: N*16 float4 threads = 4194304 -> 16384 blocks of 256.
    upsample_data_kernel<<<16384, 256, 0, stream>>>(coarse_data, out_data);
    // ijk: N*8*3 = 6291456 elems -> 24576 blocks of 256.
    upsample_ijk_kernel<<<24576, 256, 0, stream>>>(coarse_ijk, out_ijk);
}

// Round 3
// 598.005 us; speedup vs baseline: 1.0043x; 1.0043x over previous
//
#include <hip/hip_runtime.h>

// UpsamplingNearestSingle: N=262144 coarse voxels, C=64 ch, SCALE=2 -> 8 children.
// d_out (float32, concatenated): fine_data [N*8,64] then fine_ijk [N*8,3] as floats.
#define N_COARSE 262144
#define CHANNELS 64
#define DATA_BLOCKS 16384               // (N*16 float4-threads) / 256
#define IJK_ELEMS   (N_COARSE * 8 * 3)  // 6291456
#define IJK_BLOCKS  24576               // IJK_ELEMS / 256

// Native clang vector type: __builtin_nontemporal_store needs a real vector,
// not HIP's float4 class. Same 16B layout -> global_store_dwordx4 nt.
typedef float nfloat4 __attribute__((ext_vector_type(4)));

// Fused single launch. Blocks [0, DATA_BLOCKS) do feature replication
// (input-driven: each float4 of coarse_data is fetched from HBM exactly once
// and streamed to 8 child rows). Blocks [DATA_BLOCKS, ...) write fine_ijk.
// Branch is block-uniform -> zero divergence. All output stores are
// nontemporal: pure streaming writes, never re-read -> skip cache allocate.
__global__ void __launch_bounds__(256)
upsample_fused_kernel(const nfloat4* __restrict__ in, const int* __restrict__ ijk,
                      nfloat4* __restrict__ out_data, float* __restrict__ out_ijk) {
    const int b = blockIdx.x;
    if (b < DATA_BLOCKS) {
        const size_t idx = (size_t)b * 256 + threadIdx.x;  // [0, N*16)
        const size_t n  = idx >> 4;    // coarse row
        const size_t c4 = idx & 15;    // float4 index within 64-ch row
        const nfloat4 v = in[idx];
        nfloat4* base = out_data + n * 128 + c4;  // child row stride = 16 float4
#pragma unroll
        for (int o = 0; o < 8; ++o)
            __builtin_nontemporal_store(v, base + (size_t)o * 16);
    } else {
        const int e = (b - DATA_BLOCKS) * 256 + threadIdx.x;  // [0, IJK_ELEMS)
        const int r = e / 3;           // fine row (magic-mul)
        const int d = e - r * 3;       // dim 0..2
        const int n = r >> 3;          // parent voxel
        const int o = r & 7;           // child index
        const int off = (o >> (2 - d)) & 1;  // meshgrid ij-order offset bit
        __builtin_nontemporal_store((float)(ijk[n * 3 + d] * 2 + off), out_ijk + e);
    }
}

extern "C" void kernel_launch(void* const* d_in, const int* in_sizes, int n_in,
                              void* d_out, int out_size, void* d_ws, size_t ws_size,
                              hipStream_t stream) {
    const nfloat4* coarse_data = (const nfloat4*)d_in[0];
    const int*     coarse_ijk  = (const int*)d_in[1];

    float*   out      = (float*)d_out;
    nfloat4* out_data = (nfloat4*)out;
    float*   out_ijk  = out + (size_t)N_COARSE * 8 * CHANNELS;  // +134217728

    upsample_fused_kernel<<<DATA_BLOCKS + IJK_BLOCKS, 256, 0, stream>>>(
        coarse_data, coarse_ijk, out_data, out_ijk);
}